// Round 8
// baseline (179.362 us; speedup 1.0000x reference)
//
#include <hip/hip_runtime.h>
#include <hip/hip_bf16.h>

typedef __attribute__((ext_vector_type(8))) __bf16 bf16x8;
typedef __attribute__((ext_vector_type(4))) float  f32x4;

constexpr int NROW = 8192;
constexpr int DDIM = 256;
constexpr int KDIM = 512;               // packed [x | e]
constexpr int BM = 256, BN = 128, BK = 32;
constexpr int NT = KDIM / BK;           // 16 K-tiles
constexpr int ABYTES = BM * BK * 2;     // 16 KB
constexpr int BBYTES = BN * BK * 2;     // 8 KB
constexpr int BUFBYTES = ABYTES + BBYTES; // 24 KB; x2 = 48 KB total LDS

__device__ __forceinline__ void gload_lds16(const void* g, void* l) {
  __builtin_amdgcn_global_load_lds(
      (const __attribute__((address_space(1))) void*)g,
      (__attribute__((address_space(3))) void*)l, 16, 0, 0);
}

// ---------------- prep: P = [bf16(x) | bf16(exp(1-dc))], s_i = (1-p)/d*|x_i|^2
__global__ __launch_bounds__(256) void prep_kernel(
    const float* __restrict__ x, const float* __restrict__ dc,
    const float* __restrict__ pparm,
    __hip_bfloat16* __restrict__ P, float* __restrict__ s)
{
  const int row = blockIdx.x;
  const int t   = threadIdx.x;
  const float xv = x[(size_t)row * DDIM + t];
  const float ev = __expf(1.0f - dc[(size_t)row * DDIM + t]);
  P[(size_t)row * KDIM + t]        = __float2bfloat16(xv);
  P[(size_t)row * KDIM + DDIM + t] = __float2bfloat16(ev);

  float v = xv * xv;
  #pragma unroll
  for (int off = 32; off > 0; off >>= 1) v += __shfl_down(v, off, 64);
  __shared__ float red[4];
  const int lane = t & 63, wid = t >> 6;
  if (lane == 0) red[wid] = v;
  __syncthreads();
  if (t == 0) {
    const float p = pparm[0];
    s[row] = (1.0f - p) * (1.0f / (float)DDIM) * (red[0] + red[1] + red[2] + red[3]);
  }
}

// ---------------- GEMM (round-7 structure), templated on STORE for the
// decomposition probe: STORE=false runs the identical K-loop, keeps acc live
// via empty asm (no DCE, rule 17), and skips the entire store epilogue.
template <bool STORE>
__global__ void __launch_bounds__(512, 4) adj_gemm(
    const __hip_bfloat16* __restrict__ P, const float* __restrict__ s,
    const float* __restrict__ pparm, float* __restrict__ out)
{
  __shared__ __align__(16) char lds[2 * BUFBYTES];

  const float p  = pparm[0];
  const float cx = -2.0f * (1.0f - p) / (float)DDIM;
  const float ce = p / (float)DDIM;
  const float midscale = cx / ce;

  // band-major: 2048 blocks = 32 bands x 64 col-slabs (write locality).
  const int orig = blockIdx.x;
  const int bi = orig >> 6;
  const int bj = orig & 63;
  const int rowBase = bi * BM;
  const int colBase = bj * BN;

  const int tid  = threadIdx.x;
  const int lane = tid & 63;
  const int wid  = tid >> 6;               // 8 waves: wm = wid>>1 (4), wn = wid&1 (2)
  const int wmrow = (wid >> 1) * 64;
  const int wnrow = (wid & 1) * 64;
  const int frow = lane & 15;
  const int kq   = lane >> 4;

  const int cb = (kq * 16) ^ ((frow & 3) << 4);

  const int rA0  = tid >> 2;
  const int gcw  = ((tid & 3) * 16) ^ ((rA0 & 3) << 4);
  const char* Pc = (const char*)P;
  const char* gA0 = Pc + (size_t)(rowBase + rA0)       * (KDIM * 2) + gcw;
  const char* gA1 = Pc + (size_t)(rowBase + 128 + rA0) * (KDIM * 2) + gcw;
  const char* gB  = Pc + (size_t)(colBase + rA0)       * (KDIM * 2) + gcw;
  const int dA0 = tid * 16, dA1 = 8192 + tid * 16, dB = ABYTES + tid * 16;

#define STAGE(kk) do {                                   \
    char* _b = lds + ((kk) & 1) * BUFBYTES;              \
    const int _ko = (kk) * (BK * 2);                     \
    gload_lds16(gA0 + _ko, _b + dA0);                    \
    gload_lds16(gA1 + _ko, _b + dA1);                    \
    gload_lds16(gB  + _ko, _b + dB);                     \
  } while (0)

  STAGE(0);
  asm volatile("s_waitcnt vmcnt(0)" ::: "memory");
  asm volatile("s_barrier" ::: "memory");

  f32x4 acc[4][4];
  #pragma unroll
  for (int m = 0; m < 4; ++m)
    #pragma unroll
    for (int n = 0; n < 4; ++n)
      acc[m][n] = (f32x4){0.f, 0.f, 0.f, 0.f};

  #pragma unroll
  for (int t = 0; t < NT; ++t) {
    const char* buf  = lds + (t & 1) * BUFBYTES;
    const char* bufB = buf + ABYTES;

    if (t < NT - 1) STAGE(t + 1);

    bf16x8 a[4], b[4];
    #pragma unroll
    for (int i = 0; i < 4; ++i)
      a[i] = *(const bf16x8*)(buf + (wmrow + i * 16 + frow) * 64 + cb);
    #pragma unroll
    for (int j = 0; j < 4; ++j)
      b[j] = *(const bf16x8*)(bufB + (wnrow + j * 16 + frow) * 64 + cb);

    #pragma unroll
    for (int i = 0; i < 4; ++i)
      #pragma unroll
      for (int j = 0; j < 4; ++j)
        acc[i][j] = __builtin_amdgcn_mfma_f32_16x16x32_bf16(a[i], b[j], acc[i][j], 0, 0, 0);

    if (t == DDIM / BK - 1) {
      #pragma unroll
      for (int m = 0; m < 4; ++m)
        #pragma unroll
        for (int n = 0; n < 4; ++n)
          acc[m][n] *= midscale;
    }

    if (t < NT - 1) {
      asm volatile("s_waitcnt vmcnt(0)" ::: "memory");
      asm volatile("s_barrier" ::: "memory");
    }
  }

  if (!STORE) {
    // keep the whole MFMA chain live without any memory traffic (rule 17)
    #pragma unroll
    for (int m = 0; m < 4; ++m)
      #pragma unroll
      for (int n = 0; n < 4; ++n)
        #pragma unroll
        for (int r = 0; r < 4; ++r)
          asm volatile("" :: "v"(acc[m][n][r]));
    return;
  }

  // ---- epilogue: denom = s_i + s_j + ce*acc ; out = 1/denom (diag 1)
  const int rq = lane >> 4;
  #pragma unroll
  for (int n = 0; n < 4; ++n) {
    const int gcol_o = colBase + wnrow + n * 16 + frow;
    const float scol = s[gcol_o];
    #pragma unroll
    for (int m = 0; m < 4; ++m) {
      const int growb = rowBase + wmrow + m * 16 + rq * 4;
      #pragma unroll
      for (int r = 0; r < 4; ++r) {
        const int grow = growb + r;
        const float denom = s[grow] + scol + ce * acc[m][n][r];
        const float val = (grow == gcol_o) ? 1.0f : __builtin_amdgcn_rcpf(denom);
        __builtin_nontemporal_store(val, &out[(size_t)grow * NROW + gcol_o]);
      }
    }
  }
}

extern "C" void kernel_launch(void* const* d_in, const int* in_sizes, int n_in,
                              void* d_out, int out_size, void* d_ws, size_t ws_size,
                              hipStream_t stream) {
  const float* x  = (const float*)d_in[0];
  const float* dc = (const float*)d_in[1];
  const float* pp = (const float*)d_in[2];
  float* out = (float*)d_out;

  __hip_bfloat16* P = (__hip_bfloat16*)d_ws;                       // 8 MB
  float* s = (float*)((char*)d_ws + (size_t)NROW * KDIM * 2);      // +32 KB

  prep_kernel<<<NROW, 256, 0, stream>>>(x, dc, pp, P, s);
  // decomposition probe: identical K-loop without stores, then the real one.
  adj_gemm<false><<<(NROW / BM) * (NROW / BN), 512, 0, stream>>>(P, s, pp, out);
  adj_gemm<true ><<<(NROW / BM) * (NROW / BN), 512, 0, stream>>>(P, s, pp, out);
}

// Round 9
// 145.696 us; speedup vs baseline: 1.2311x; 1.2311x over previous
//
#include <hip/hip_runtime.h>
#include <hip/hip_bf16.h>

typedef __attribute__((ext_vector_type(8))) __bf16 bf16x8;
typedef __attribute__((ext_vector_type(4))) float  f32x4;

constexpr int NROW = 8192;
constexpr int DDIM = 256;
constexpr int KDIM = 512;                 // packed [x | e]
constexpr int BM = 256, BN = 128, BK = 64;
constexpr int ABY = BM * BK * 2;          // 32 KB
constexpr int BBY = BN * BK * 2;          // 16 KB
constexpr int BUF = ABY + BBY;            // 48 KB
constexpr int SOFF = 3 * BUF;             // 144 KB: then srow 1KB, scol 512B
constexpr int LDS_TOTAL = SOFF + 1536;    // 148992 B

__device__ __forceinline__ void gload_lds16(const void* g, void* l) {
  __builtin_amdgcn_global_load_lds(
      (const __attribute__((address_space(1))) void*)g,
      (__attribute__((address_space(3))) void*)l, 16, 0, 0);
}

// ---------------- prep: P = [bf16(x) | bf16(exp(1-dc))], s_i = (1-p)/d*|x_i|^2
__global__ __launch_bounds__(256) void prep_kernel(
    const float* __restrict__ x, const float* __restrict__ dc,
    const float* __restrict__ pparm,
    __hip_bfloat16* __restrict__ P, float* __restrict__ s)
{
  const int row = blockIdx.x;
  const int t   = threadIdx.x;
  const float xv = x[(size_t)row * DDIM + t];
  const float ev = __expf(1.0f - dc[(size_t)row * DDIM + t]);
  P[(size_t)row * KDIM + t]        = __float2bfloat16(xv);
  P[(size_t)row * KDIM + DDIM + t] = __float2bfloat16(ev);

  float v = xv * xv;
  #pragma unroll
  for (int off = 32; off > 0; off >>= 1) v += __shfl_down(v, off, 64);
  __shared__ float red[4];
  const int lane = t & 63, wid = t >> 6;
  if (lane == 0) red[wid] = v;
  __syncthreads();
  if (t == 0) {
    const float p = pparm[0];
    s[row] = (1.0f - p) * (1.0f / (float)DDIM) * (red[0] + red[1] + red[2] + red[3]);
  }
}

// ---------------- persistent GEMM: 256 blocks (1/CU), each 8 tiles of 256x128.
// Drip-store previous tile's 64 outputs (8/period) during current K-loop;
// 3-buf LDS, depth-2 counted vmcnt (never 0 in steady state).
__global__ void __launch_bounds__(512, 2) adj_gemm(
    const __hip_bfloat16* __restrict__ P, const float* __restrict__ sG,
    const float* __restrict__ pparm, float* __restrict__ out)
{
  extern __shared__ char lds[];

  const float p  = pparm[0];
  const float cx = -2.0f * (1.0f - p) / (float)DDIM;
  const float ce = p / (float)DDIM;
  const float midscale = cx / ce;

  const int blk  = blockIdx.x;           // 256 blocks
  const int bi   = blk >> 3;             // 0..31: 256-row band
  const int colg = blk & 7;              // 0..7: 1024-col group (8 tiles)
  const int rowBase = bi * BM;

  const int tid  = threadIdx.x;
  const int lane = tid & 63;
  const int wid  = tid >> 6;             // 8 waves: wm=wid>>1 (4), wn=wid&1 (2)
  const int wmrow = (wid >> 1) * 64;
  const int wnrow = (wid & 1) * 64;
  const int frow = lane & 15;
  const int kq   = lane >> 4;            // also rq for C-fragment rows

  // ---- staging bases: one A ptr + one B ptr (j strides fold to +64KB)
  const int qr   = tid >> 3;             // row 0..63 within 64-row group
  const int cbsw = ((tid & 7) * 16) ^ ((qr & 7) << 4);   // pre-swizzled src col
  const char* Pc  = (const char*)P;
  const char* bA0 = Pc + (size_t)(rowBase + qr)      * 1024 + cbsw;
  const char* bB0 = Pc + (size_t)(colg * 1024 + qr)  * 1024 + cbsw;
  const int   d0  = tid * 16;

  // stage tile (sub2, k-tile t2) into bufp: 4 A loads + 2 B loads
#define STAGE(bufp, sub2, t2) do {                                          \
    gload_lds16(bA0 +           (t2) * 128, (bufp) + d0);                   \
    gload_lds16(bA0 + 65536 +   (t2) * 128, (bufp) + d0 + 8192);            \
    gload_lds16(bA0 + 131072 +  (t2) * 128, (bufp) + d0 + 16384);           \
    gload_lds16(bA0 + 196608 +  (t2) * 128, (bufp) + d0 + 24576);           \
    gload_lds16(bB0 + (size_t)(sub2) * 131072 + (t2) * 128,                 \
                (bufp) + ABY + d0);                                         \
    gload_lds16(bB0 + 65536 + (size_t)(sub2) * 131072 + (t2) * 128,         \
                (bufp) + ABY + d0 + 8192);                                  \
  } while (0)

  // ---- prologue: srow -> LDS (1KB, dup across waves), stage (0,0),(0,1)
  gload_lds16((const char*)sG + (size_t)rowBase * 4 + lane * 16,
              lds + SOFF + lane * 16);
  STAGE(lds,       0, 0);
  STAGE(lds + BUF, 0, 1);
  asm volatile("s_waitcnt vmcnt(6)" ::: "memory");   // srow + batch(0) landed
  asm volatile("s_barrier" ::: "memory");

  f32x4 acc[4][4], pend[4][4];
  #pragma unroll
  for (int m = 0; m < 4; ++m)
    #pragma unroll
    for (int n = 0; n < 4; ++n)
      acc[m][n] = (f32x4){0.f, 0.f, 0.f, 0.f};

  // per-thread output base (row part): rows rowBase+wmrow+kq*4, col wnrow+frow
  float* outP = out + (size_t)(rowBase + wmrow + kq * 4) * NROW + wnrow + frow;
  const float* sRow = (const float*)(lds + SOFF);
  const float* sCol = (const float*)(lds + SOFF + 1024);

  int cur = 0;
  for (int sub = 0; sub < 8; ++sub) {
    #pragma unroll
    for (int t = 0; t < 8; ++t) {
      char* buf  = lds + cur * BUF;
      const int nx = (cur >= 1) ? cur - 1 : cur + 2;   // (cur+2)%3
      char* nbuf = lds + nx * BUF;

      // ---- drip: 8 NT stores of prev tile's pend chunk t (oldest VMEM ops)
      if (sub > 0) {
        const int m = t >> 1;
        const int colPrev = (colg * 8 + sub - 1) * 128;
        #pragma unroll
        for (int nn = 0; nn < 2; ++nn) {
          const int n = (t & 1) * 2 + nn;
          #pragma unroll
          for (int r = 0; r < 4; ++r)
            __builtin_nontemporal_store(pend[m][n][r],
                outP + (size_t)(m * 16 + r) * NROW + colPrev + n * 16);
        }
      }

      // ---- stage batch for period p+2
      if (t <= 5)       STAGE(nbuf, sub, t + 2);
      else if (sub < 7) STAGE(nbuf, sub + 1, t - 6);
      // s-copy for current tile's cols (used at t==7); counted: vmcnt(7) below
      if (t == 4) {
        if (lane < 32)
          gload_lds16((const char*)sG + (size_t)((colg * 8 + sub) * 128) * 4 + lane * 16,
                      lds + SOFF + 1024 + lane * 16);
      }

      // ---- phase 0: A frags + B n=0,1
      bf16x8 a[4][2], b[2][2];
      #pragma unroll
      for (int m = 0; m < 4; ++m) {
        const int r = wmrow + m * 16 + frow;
        #pragma unroll
        for (int ks = 0; ks < 2; ++ks)
          a[m][ks] = *(const bf16x8*)(buf + r * 128 +
                        ((ks * 64 + kq * 16) ^ ((r & 7) << 4)));
      }
      #pragma unroll
      for (int n = 0; n < 2; ++n) {
        const int r = wnrow + n * 16 + frow;
        #pragma unroll
        for (int ks = 0; ks < 2; ++ks)
          b[n][ks] = *(const bf16x8*)(buf + ABY + r * 128 +
                        ((ks * 64 + kq * 16) ^ ((r & 7) << 4)));
      }
      __builtin_amdgcn_s_setprio(1);
      #pragma unroll
      for (int m = 0; m < 4; ++m)
        #pragma unroll
        for (int n = 0; n < 2; ++n)
          #pragma unroll
          for (int ks = 0; ks < 2; ++ks)
            acc[m][n] = __builtin_amdgcn_mfma_f32_16x16x32_bf16(a[m][ks], b[n][ks], acc[m][n], 0, 0, 0);
      __builtin_amdgcn_s_setprio(0);

      // ---- phase 1: B n=2,3
      #pragma unroll
      for (int n = 0; n < 2; ++n) {
        const int r = wnrow + (2 + n) * 16 + frow;
        #pragma unroll
        for (int ks = 0; ks < 2; ++ks)
          b[n][ks] = *(const bf16x8*)(buf + ABY + r * 128 +
                        ((ks * 64 + kq * 16) ^ ((r & 7) << 4)));
      }
      __builtin_amdgcn_s_setprio(1);
      #pragma unroll
      for (int m = 0; m < 4; ++m)
        #pragma unroll
        for (int n = 0; n < 2; ++n)
          #pragma unroll
          for (int ks = 0; ks < 2; ++ks)
            acc[m][2 + n] = __builtin_amdgcn_mfma_f32_16x16x32_bf16(a[m][ks], b[n][ks], acc[m][2 + n], 0, 0, 0);
      __builtin_amdgcn_s_setprio(0);

      if (t == 3) {                        // x-segment (k<256) done
        #pragma unroll
        for (int m = 0; m < 4; ++m)
          #pragma unroll
          for (int n = 0; n < 4; ++n)
            acc[m][n] *= midscale;
      }

      if (t == 7) {                        // epilogue -> pend; re-zero acc
        const int colB = (colg * 8 + sub) * 128;
        #pragma unroll
        for (int m = 0; m < 4; ++m) {
          const f32x4 sr = *(const f32x4*)&sRow[wmrow + m * 16 + kq * 4];
          #pragma unroll
          for (int n = 0; n < 4; ++n) {
            const float sc = sCol[wnrow + n * 16 + frow];
            const int gcol = colB + wnrow + n * 16 + frow;
            #pragma unroll
            for (int r = 0; r < 4; ++r) {
              const int grow = rowBase + wmrow + m * 16 + kq * 4 + r;
              const float denom = sr[r] + sc + ce * acc[m][n][r];
              pend[m][n][r] = (grow == gcol) ? 1.0f : __builtin_amdgcn_rcpf(denom);
            }
            acc[m][n] = (f32x4){0.f, 0.f, 0.f, 0.f};
          }
        }
      }

      // ---- boundary: retire batch(p-1)+drips, keep batch(p) in flight
      if (t == 4)                 asm volatile("s_waitcnt vmcnt(7)" ::: "memory");
      else if (t <= 5)            asm volatile("s_waitcnt vmcnt(6)" ::: "memory");
      else {                      // t==6 or t==7
        if (sub < 7)              asm volatile("s_waitcnt vmcnt(6)" ::: "memory");
        else                      asm volatile("s_waitcnt vmcnt(0)" ::: "memory");
      }
      asm volatile("s_barrier" ::: "memory");
      cur = (cur >= 2) ? 0 : cur + 1;
    }
  }

  // ---- tail: drain sub 7's pend
  {
    const int colPrev = (colg * 8 + 7) * 128;
    #pragma unroll
    for (int m = 0; m < 4; ++m)
      #pragma unroll
      for (int n = 0; n < 4; ++n)
        #pragma unroll
        for (int r = 0; r < 4; ++r)
          __builtin_nontemporal_store(pend[m][n][r],
              outP + (size_t)(m * 16 + r) * NROW + colPrev + n * 16);
  }
}

extern "C" void kernel_launch(void* const* d_in, const int* in_sizes, int n_in,
                              void* d_out, int out_size, void* d_ws, size_t ws_size,
                              hipStream_t stream) {
  const float* x  = (const float*)d_in[0];
  const float* dc = (const float*)d_in[1];
  const float* pp = (const float*)d_in[2];
  float* out = (float*)d_out;

  __hip_bfloat16* P = (__hip_bfloat16*)d_ws;                       // 8 MB
  float* s = (float*)((char*)d_ws + (size_t)NROW * KDIM * 2);      // +32 KB

  hipFuncSetAttribute(reinterpret_cast<const void*>(adj_gemm),
                      hipFuncAttributeMaxDynamicSharedMemorySize, LDS_TOTAL);

  prep_kernel<<<NROW, 256, 0, stream>>>(x, dc, pp, P, s);
  adj_gemm<<<256, 512, LDS_TOTAL, stream>>>(P, s, pp, out);
}

// Round 10
// 117.864 us; speedup vs baseline: 1.5218x; 1.2361x over previous
//
#include <hip/hip_runtime.h>
#include <hip/hip_bf16.h>

typedef __attribute__((ext_vector_type(8))) __bf16 bf16x8;
typedef __attribute__((ext_vector_type(4))) float  f32x4;

constexpr int NROW = 8192;
constexpr int KDIM = 512;               // packed [x | e]
constexpr int BK = 32;
constexpr int ABY = 256 * BK * 2;       // 16 KB (A: 256 rows)
constexpr int BBY = 128 * BK * 2;       // 8 KB  (B: 128 rows)
constexpr int BUF = ABY + BBY;          // 24 KB
constexpr int SOFF = 3 * BUF;           // 72 KB, then srow 1KB + scol 512B
constexpr int LDS_TOTAL = SOFF + 1536;

#define VMW(N) asm volatile("s_waitcnt vmcnt(" #N ")" ::: "memory")
#define BAR()  asm volatile("s_barrier" ::: "memory")

__device__ __forceinline__ void gload_lds16(const void* g, void* l) {
  __builtin_amdgcn_global_load_lds(
      (const __attribute__((address_space(1))) void*)g,
      (__attribute__((address_space(3))) void*)l, 16, 0, 0);
}

// ---- prep (vectorized): P = [bf16(x)|bf16(exp(1-dc))], s_i = (1-p)/d*|x_i|^2
__global__ __launch_bounds__(256) void prep_kernel(
    const float* __restrict__ x, const float* __restrict__ dc,
    const float* __restrict__ pparm,
    __hip_bfloat16* __restrict__ P, float* __restrict__ s)
{
  const int t   = threadIdx.x;
  const int row = blockIdx.x * 4 + (t >> 6);
  const int e4  = (t & 63) * 4;
  const f32x4 xv = *(const f32x4*)&x[(size_t)row * 256 + e4];
  const f32x4 dv = *(const f32x4*)&dc[(size_t)row * 256 + e4];
  __hip_bfloat16 hx[4], he[4];
  float ss = 0.f;
  #pragma unroll
  for (int j = 0; j < 4; ++j) {
    hx[j] = __float2bfloat16(xv[j]);
    ss += xv[j] * xv[j];
    he[j] = __float2bfloat16(__expf(1.0f - dv[j]));
  }
  *(ushort4*)&P[(size_t)row * 512 + e4]       = *(ushort4*)hx;
  *(ushort4*)&P[(size_t)row * 512 + 256 + e4] = *(ushort4*)he;
  #pragma unroll
  for (int off = 32; off > 0; off >>= 1) ss += __shfl_down(ss, off, 64);
  if ((t & 63) == 0) {
    const float p = pparm[0];
    s[row] = (1.0f - p) * (1.0f / 256.0f) * ss;
  }
}

// ---- persistent GEMM: 256 blocks (1/CU), 8 tiles (256x128) per block.
// Round-4 period body; 3-buf depth-2 prefetch; drip stores with a
// STORE-AWARE vmcnt ledger (stores count in vmcnt, retire in order).
__global__ void __launch_bounds__(512, 2) adj_gemm(
    const __hip_bfloat16* __restrict__ P, const float* __restrict__ sG,
    const float* __restrict__ pparm, float* __restrict__ out)
{
  extern __shared__ char lds[];

  const float p  = pparm[0];
  const float cx = -2.0f * (1.0f - p) / 256.0f;
  const float ce = p / 256.0f;
  const float midscale = cx / ce;

  // XCD patch: xcd owns 8 bands x 4 col-groups (A 2MB + B 4MB working set)
  const int blk = blockIdx.x;
  const int xcd = blk & 7, ii = blk >> 3;
  const int band = (xcd >> 1) * 8 + (ii & 7);   // 0..31
  const int grp  = (xcd & 1) * 4 + (ii >> 3);   // 0..7
  const int rowBase = band * 256;
  const int colGrp  = grp * 1024;

  const int tid  = threadIdx.x;
  const int lane = tid & 63;
  const int wid  = tid >> 6;              // 8 waves: 4M x 2N, per-wave 64x64
  const int wmrow = (wid >> 1) * 64;
  const int wnrow = (wid & 1) * 64;
  const int frow = lane & 15;
  const int kq   = lane >> 4;

  const int cb = (kq * 16) ^ ((frow & 3) << 4);   // swizzled frag col-byte

  const int rA0 = tid >> 2;
  const int gcw = ((tid & 3) * 16) ^ ((rA0 & 3) << 4);
  const char* Pc  = (const char*)P;
  const char* gA0 = Pc + (size_t)(rowBase + rA0) * 1024 + gcw;
  const char* gA1 = gA0 + 128 * 1024;
  const char* gB0 = Pc + (size_t)(colGrp + rA0) * 1024 + gcw;
  const int dA0 = tid * 16, dA1 = 8192 + tid * 16, dB = ABY + tid * 16;

#define STAGE(sub2, kt2, bufp) do {                                   \
    gload_lds16(gA0 + (kt2) * 64, (bufp) + dA0);                      \
    gload_lds16(gA1 + (kt2) * 64, (bufp) + dA1);                      \
    gload_lds16(gB0 + (size_t)(sub2) * 131072 + (kt2) * 64, (bufp) + dB); \
  } while (0)

  // prologue: srow (all waves dup), T(0), T(1)
  gload_lds16((const char*)sG + (size_t)rowBase * 4 + lane * 16,
              lds + SOFF + lane * 16);
  STAGE(0, 0, lds);
  STAGE(0, 1, lds + BUF);
  VMW(3); BAR();

  f32x4 acc[4][4], pend[4][4];
  #pragma unroll
  for (int m = 0; m < 4; ++m)
    #pragma unroll
    for (int n = 0; n < 4; ++n)
      acc[m][n] = (f32x4){0.f, 0.f, 0.f, 0.f};

  float* outRowP = out + (size_t)(rowBase + wmrow + kq * 4) * NROW;
  const float* sRow = (const float*)(lds + SOFF);
  const float* sCol = (const float*)(lds + SOFF + 1024);

  int cur = 0;
  for (int sub = 0; sub < 8; ++sub) {
    #pragma unroll
    for (int t = 0; t < 16; ++t) {
      char* buf  = lds + cur * BUF;
      const int n2 = (cur >= 1) ? cur - 1 : 2;      // (cur+2)%3
      char* nbuf = lds + n2 * BUF;

      // 1) stage T(g+2)  (loads FIRST — ledger order [L, scol, S])
      if (t <= 13)                    STAGE(sub, t + 2, nbuf);
      else if (sub < 7 && t == 14)    STAGE(sub + 1, 0, nbuf);
      else if (sub < 7)               STAGE(sub + 1, 1, nbuf);
      // 2) scol for this tile (used at t==15); all waves dup, lanes<32
      if (t == 13 && lane < 32)
        gload_lds16((const char*)sG + (size_t)(colGrp + sub * 128) * 4 + lane * 16,
                    lds + SOFF + 1024 + lane * 16);
      // 3) drip: 4 NT stores of prev tile's pend (newest vm-ops, 2-period slack)
      if (sub > 0) {
        const int m = t >> 2, n = t & 3;
        float* op = outRowP + (size_t)(m * 16) * NROW
                    + colGrp + (sub - 1) * 128 + wnrow + n * 16 + frow;
        #pragma unroll
        for (int r = 0; r < 4; ++r)
          __builtin_nontemporal_store(pend[m][n][r], op + (size_t)r * NROW);
      }

      // 4) fragments
      bf16x8 a[4], b[4];
      #pragma unroll
      for (int i = 0; i < 4; ++i)
        a[i] = *(const bf16x8*)(buf + (wmrow + i * 16 + frow) * 64 + cb);
      #pragma unroll
      for (int j = 0; j < 4; ++j)
        b[j] = *(const bf16x8*)(buf + ABY + (wnrow + j * 16 + frow) * 64 + cb);

      // 5) MFMA
      __builtin_amdgcn_s_setprio(1);
      #pragma unroll
      for (int i = 0; i < 4; ++i)
        #pragma unroll
        for (int j = 0; j < 4; ++j)
          acc[i][j] = __builtin_amdgcn_mfma_f32_16x16x32_bf16(a[i], b[j], acc[i][j], 0, 0, 0);
      __builtin_amdgcn_s_setprio(0);

      if (t == 7) {                       // x-segment done: acc *= cx/ce
        #pragma unroll
        for (int m = 0; m < 4; ++m)
          #pragma unroll
          for (int n = 0; n < 4; ++n)
            acc[m][n] *= midscale;
      }

      // 6) period-end wait: exact store-aware ledger
      if (sub == 0)                 VMW(3);
      else if (sub == 1 && t == 0)  VMW(7);
      else if (sub == 7 && t == 14) VMW(9);
      else if (sub == 7 && t == 15) VMW(12);
      else                          VMW(11);
      BAR();

      // 7) tile epilogue -> pend (scol guaranteed landed: issued 2 periods back)
      if (t == 15) {
        const int colB = colGrp + sub * 128;
        #pragma unroll
        for (int m = 0; m < 4; ++m) {
          const f32x4 sr = *(const f32x4*)&sRow[wmrow + m * 16 + kq * 4];
          #pragma unroll
          for (int n = 0; n < 4; ++n) {
            const int gcol = colB + wnrow + n * 16 + frow;
            const float sc = sCol[wnrow + n * 16 + frow];
            #pragma unroll
            for (int r = 0; r < 4; ++r) {
              const int grow = rowBase + wmrow + m * 16 + kq * 4 + r;
              const float denom = sr[r] + sc + ce * acc[m][n][r];
              pend[m][n][r] = (grow == gcol) ? 1.0f : __builtin_amdgcn_rcpf(denom);
            }
            acc[m][n] = (f32x4){0.f, 0.f, 0.f, 0.f};
          }
        }
      }
      cur = (cur >= 2) ? 0 : cur + 1;
    }
  }

  // tail: tile 7's pend
  {
    const int colP = colGrp + 7 * 128;
    #pragma unroll
    for (int m = 0; m < 4; ++m)
      #pragma unroll
      for (int n = 0; n < 4; ++n) {
        float* op = outRowP + (size_t)(m * 16) * NROW + colP + wnrow + n * 16 + frow;
        #pragma unroll
        for (int r = 0; r < 4; ++r)
          __builtin_nontemporal_store(pend[m][n][r], op + (size_t)r * NROW);
      }
  }
}

extern "C" void kernel_launch(void* const* d_in, const int* in_sizes, int n_in,
                              void* d_out, int out_size, void* d_ws, size_t ws_size,
                              hipStream_t stream) {
  const float* x  = (const float*)d_in[0];
  const float* dc = (const float*)d_in[1];
  const float* pp = (const float*)d_in[2];
  float* out = (float*)d_out;

  __hip_bfloat16* P = (__hip_bfloat16*)d_ws;                       // 8 MB
  float* s = (float*)((char*)d_ws + (size_t)NROW * KDIM * 2);      // +32 KB

  hipFuncSetAttribute(reinterpret_cast<const void*>(adj_gemm),
                      hipFuncAttributeMaxDynamicSharedMemorySize, LDS_TOTAL);

  prep_kernel<<<NROW / 4, 256, 0, stream>>>(x, dc, pp, P, s);
  adj_gemm<<<256, 512, LDS_TOTAL, stream>>>(P, s, pp, out);
}